// Round 5
// baseline (655.155 us; speedup 1.0000x reference)
//
#include <hip/hip_runtime.h>
#include <hip/hip_bf16.h>
#include <math.h>

#define VD 32000

typedef __attribute__((ext_vector_type(8))) short short8;
typedef __attribute__((ext_vector_type(4))) float floatx4;

__device__ __forceinline__ short f2bf(float f) {
    unsigned u = __builtin_bit_cast(unsigned, f);
    u += 0x7FFFu + ((u >> 16) & 1u);
    return (short)(u >> 16);
}
__device__ __forceinline__ float bf2f(short h) {
    unsigned u = ((unsigned)(unsigned short)h) << 16;
    return __builtin_bit_cast(float, u);
}
__device__ __forceinline__ unsigned pack2(float a, float b) {
    unsigned ua = __builtin_bit_cast(unsigned, a) + 0x8000u;
    unsigned ub = __builtin_bit_cast(unsigned, b) + 0x8000u;
    return (ub & 0xffff0000u) | (ua >> 16);
}
__device__ __forceinline__ void split8(const float4 u0, const float4 u1,
                                       short8* hi, short8* lo) {
    float f[8] = {u0.x, u0.y, u0.z, u0.w, u1.x, u1.y, u1.z, u1.w};
#pragma unroll
    for (int j = 0; j < 8; ++j) {
        short h = f2bf(f[j]);
        (*hi)[j] = h;
        (*lo)[j] = f2bf(f[j] - bf2f(h));
    }
}
__device__ __forceinline__ short8 pack8(const float4 u0, const float4 u1) {
    union { unsigned u[4]; short8 s; } pk;
    pk.u[0] = pack2(u0.x, u0.y); pk.u[1] = pack2(u0.z, u0.w);
    pk.u[2] = pack2(u1.x, u1.y); pk.u[3] = pack2(u1.z, u1.w);
    return pk.s;
}

#define MFMA(a, b, c) __builtin_amdgcn_mfma_f32_16x16x32_bf16(a, b, c, 0, 0, 0)

// Manual grid barrier: works in a normal launch because 512 blocks at
// __launch_bounds__(256,2) + 17.3 KB LDS are guaranteed 2-per-CU co-resident
// on 256 CUs. threadfence = device-scope release/acquire (flush + L1 inv).
__device__ __forceinline__ void gbar(unsigned* bar, int ph, unsigned nb) {
    __syncthreads();
    if (threadIdx.x == 0) {
        __threadfence();
        __atomic_fetch_add(bar + ph, 1u, __ATOMIC_RELAXED);
        while (__atomic_load_n(bar + ph, __ATOMIC_RELAXED) < nb)
            __builtin_amdgcn_s_sleep(2);
        __threadfence();
    }
    __syncthreads();
}

// Frag-pattern: for 16x16x32 bf16 MFMA, lane l (i=l&15, q=l>>4) holds
// A[m=i][k=q*8+j] and B[k=q*8+j][n=i] -- 8 consecutive k of one row, so
// activation frags are built from plain fp32 row loads.
// combh layout: element M[b][k] at ((t*2+mt)*64 + q*16 + i)*8 + j with
// t=k/32, q=(k%32)/8, j=k%8, mt=b/16, i=b%16.

__global__ __launch_bounds__(256, 2) void mega(
    const float* __restrict__ x0, const float* __restrict__ enc,
    const float* __restrict__ h0,
    const float* __restrict__ W_ih, const float* __restrict__ W_hh,
    const float* __restrict__ b_ih, const float* __restrict__ b_hh,
    const float* __restrict__ W_attn, const float* __restrict__ W_comb,
    const float* __restrict__ b_comb, const float* __restrict__ W_out,
    const float* __restrict__ b_out, float* __restrict__ out,
    float* __restrict__ ws)
{
    const int gid = blockIdx.x, tid = threadIdx.x;
    const unsigned NB = gridDim.x;          // 512
    const int gt = gid * 256 + tid;
    const int wv = tid >> 6, l = tid & 63;
    const int i = l & 15, q = l >> 4;

    unsigned* bar = (unsigned*)ws;          // 16 counters (pre-zeroed by memset)
    float* wsf   = ws + 16;
    float* xg    = wsf;                   // 98304  (zeroed in P0)
    float* hg    = xg + 98304;            // 98304
    float* v     = hg + 98304;            // 32768
    float* num   = v + 32768;             // 32768
    float* den   = num + 32768;           // 32
    float* sexp  = den + 32;              // 32
    float* comb  = sexp + 32;             // 32768  -- zero region: 294976 floats
    float* es    = comb + 32768;          // 4096
    float* dec   = es + 4096;             // 32768
    short* combh = (short*)(dec + 32768); // 32768 shorts

    __shared__ float stage[32][65];
    __shared__ float eplds[4][32][17];
    __shared__ float bsum[32];
    __shared__ float red[4][8];
    __shared__ float esl[8];

    // ---- P0: zero accumulators (294976 floats = 73744 float4) -----------
    {
        float4* z4 = (float4*)wsf;
        if (gt < 73744) z4[gt] = make_float4(0.f, 0.f, 0.f, 0.f);
    }
    gbar(bar, 0, NB);

    // ---- P1: gate GEMMs  xg += x0.W_ih^T, hg += h0.W_hh^T (hi/lo) -------
    if (gid < 384) {
        const int z = gid & 1, kc = (gid >> 1) & 3, nt = gid >> 3;
        const int n0 = nt * 64 + wv * 16, k0 = kc * 256;
        const float* W   = z ? W_hh : W_ih;
        const float* act = z ? h0   : x0;
        float*       o   = z ? hg   : xg;
        const float* wrow = W + (size_t)(n0 + i) * 1024 + q * 8;
        const float* a0 = act + (size_t)i * 1024 + q * 8;
        const float* a1 = act + (size_t)(16 + i) * 1024 + q * 8;
        floatx4 acc0 = {0.f,0.f,0.f,0.f}, acc1 = {0.f,0.f,0.f,0.f};
#pragma unroll 2
        for (int kk = k0; kk < k0 + 256; kk += 32) {
            float4 w0 = *(const float4*)(wrow + kk);
            float4 w1 = *(const float4*)(wrow + kk + 4);
            float4 p0 = *(const float4*)(a0 + kk);
            float4 p1 = *(const float4*)(a0 + kk + 4);
            float4 r0 = *(const float4*)(a1 + kk);
            float4 r1 = *(const float4*)(a1 + kk + 4);
            short8 ah, al, b0h, b0l, b1h, b1l;
            split8(w0, w1, &ah, &al);
            split8(p0, p1, &b0h, &b0l);
            split8(r0, r1, &b1h, &b1l);
            acc0 = MFMA(ah, b0h, acc0);
            acc0 = MFMA(ah, b0l, acc0);
            acc0 = MFMA(al, b0h, acc0);
            acc1 = MFMA(ah, b1h, acc1);
            acc1 = MFMA(ah, b1l, acc1);
            acc1 = MFMA(al, b1h, acc1);
        }
#pragma unroll
        for (int r = 0; r < 4; ++r) {
            eplds[wv][i][q * 4 + r]      = acc0[r];   // D[m=q*4+r][n=i]
            eplds[wv][i + 16][q * 4 + r] = acc1[r];
        }
        int b = l >> 1, hf = l & 1;
        size_t obase = (size_t)b * 3072 + n0 + hf * 8;
#pragma unroll
        for (int t = 0; t < 8; ++t)
            atomicAdd(o + obase + t, eplds[wv][b][hf * 8 + t]);
    }
    gbar(bar, 1, NB);

    // ---- P2: GRU gate fusion -> dec (fp32) ------------------------------
    if (gt < 32768) {
        int b = gt >> 10, h = gt & 1023;
        const float* xp = xg + (size_t)b * 3072 + h;
        const float* hp = hg + (size_t)b * 3072 + h;
        float r = 1.f / (1.f + __expf(-(xp[0] + b_ih[h] + hp[0] + b_hh[h])));
        float z = 1.f / (1.f + __expf(-(xp[1024] + b_ih[1024 + h] +
                                        hp[1024] + b_hh[1024 + h])));
        float n = tanhf(xp[2048] + b_ih[2048 + h] +
                        r * (hp[2048] + b_hh[2048 + h]));
        dec[gt] = (1.f - z) * n + z * h0[gt];
    }
    gbar(bar, 2, NB);

    // ---- P3: v[b][e] += dec[b][:].W_attn[:][1024+e] ---------------------
    if (gid < 256) {
        const int et = gid & 15, kc = gid >> 4;
        const int e0 = et * 64, k0 = kc * 64;
        const int sr = tid >> 3, sc = (tid & 7) * 8;
        floatx4 acc0 = {0.f,0.f,0.f,0.f}, acc1 = {0.f,0.f,0.f,0.f};
#pragma unroll
        for (int t = 0; t < 2; ++t) {
            int kb = k0 + t * 32;
            const float* src = W_attn + (size_t)(kb + sr) * 2048 + 1024 + e0 + sc;
            float4 s0 = *(const float4*)src;
            float4 s1 = *(const float4*)(src + 4);
            __syncthreads();
            *(float4*)&stage[sr][sc]     = s0;
            *(float4*)&stage[sr][sc + 4] = s1;
            __syncthreads();
            short8 Ah0, Al0, Ah1, Al1, Bh, Bl;
            {
                const float* dp = dec + (size_t)i * 1024 + kb + q * 8;
                split8(*(const float4*)dp, *(const float4*)(dp + 4), &Ah0, &Al0);
                const float* dp1 = dec + (size_t)(16 + i) * 1024 + kb + q * 8;
                split8(*(const float4*)dp1, *(const float4*)(dp1 + 4), &Ah1, &Al1);
            }
#pragma unroll
            for (int j = 0; j < 8; ++j) {
                float f = stage[q * 8 + j][wv * 16 + i];
                unsigned u = __builtin_bit_cast(unsigned, f);
                float hif = __builtin_bit_cast(float, u & 0xffff0000u);
                Bh[j] = (short)(u >> 16);
                Bl[j] = (short)(__builtin_bit_cast(unsigned, f - hif) >> 16);
            }
            acc0 = MFMA(Ah0, Bh, acc0);
            acc0 = MFMA(Ah0, Bl, acc0);
            acc0 = MFMA(Al0, Bh, acc0);
            acc1 = MFMA(Ah1, Bh, acc1);
            acc1 = MFMA(Ah1, Bl, acc1);
            acc1 = MFMA(Al1, Bh, acc1);
        }
#pragma unroll
        for (int r = 0; r < 4; ++r) {
            atomicAdd(v + (size_t)(q * 4 + r) * 1024 + e0 + wv * 16 + i, acc0[r]);
            atomicAdd(v + (size_t)(16 + q * 4 + r) * 1024 + e0 + wv * 16 + i, acc1[r]);
        }
    }
    gbar(bar, 3, NB);

    // ---- P4: scores + shift-free softmax partials + context partials ----
    {
        int b = gid & 31, s0 = (gid >> 5) * 8;
        float4 vv = *((const float4*)(v + (size_t)b * 1024) + tid);
        float4 e8[8];
        float part[8];
#pragma unroll
        for (int s = 0; s < 8; ++s) {
            float4 e4 = *((const float4*)(enc + ((size_t)(s0 + s) * 32 + b) * 1024) + tid);
            e8[s] = e4;
            part[s] = e4.x * vv.x + e4.y * vv.y + e4.z * vv.z + e4.w * vv.w;
        }
#pragma unroll
        for (int s = 0; s < 8; ++s) {
            float p = part[s];
            for (int o = 32; o; o >>= 1) p += __shfl_down(p, o);
            if (l == 0) red[wv][s] = p;
        }
        __syncthreads();
        if (tid < 8) {
            float sc_ = red[0][tid] + red[1][tid] + red[2][tid] + red[3][tid];
            float e = __expf(sc_);
            esl[tid] = e;
            es[b * 128 + s0 + tid] = e;
        }
        __syncthreads();
        if (tid == 0) {
            float ds = 0.f;
#pragma unroll
            for (int s = 0; s < 8; ++s) ds += esl[s];
            atomicAdd(den + b, ds);
        }
        float n0 = 0.f, n1 = 0.f, n2 = 0.f, n3 = 0.f;
#pragma unroll
        for (int s = 0; s < 8; ++s) {
            float e = esl[s];
            n0 += e * e8[s].x; n1 += e * e8[s].y;
            n2 += e * e8[s].z; n3 += e * e8[s].w;
        }
        float* np = num + (size_t)b * 1024 + tid * 4;
        atomicAdd(np, n0); atomicAdd(np + 1, n1);
        atomicAdd(np + 2, n2); atomicAdd(np + 3, n3);
    }
    gbar(bar, 4, NB);

    // ---- P5: comb GEMM (cat built per-lane) + aw_out --------------------
    if (gid < 128) {
        const int nt = gid & 15, kc = gid >> 4;
        const int n0 = nt * 64 + wv * 16, k0 = kc * 256;
        const bool isnum = kc >= 4;
        const float* base = isnum ? num : x0;
        const int kb = isnum ? k0 - 1024 : k0;
        float rd0 = 1.f, rd1 = 1.f;
        if (isnum) { rd0 = 1.f / den[i]; rd1 = 1.f / den[16 + i]; }
        const float* wrow = W_comb + (size_t)(n0 + i) * 2048 + k0 + q * 8;
        const float* a0 = base + (size_t)i * 1024 + kb + q * 8;
        const float* a1 = base + (size_t)(16 + i) * 1024 + kb + q * 8;
        floatx4 acc0 = {0.f,0.f,0.f,0.f}, acc1 = {0.f,0.f,0.f,0.f};
#pragma unroll 2
        for (int kk = 0; kk < 256; kk += 32) {
            float4 w0 = *(const float4*)(wrow + kk);
            float4 w1 = *(const float4*)(wrow + kk + 4);
            float4 p0 = *(const float4*)(a0 + kk);
            float4 p1 = *(const float4*)(a0 + kk + 4);
            float4 r0 = *(const float4*)(a1 + kk);
            float4 r1 = *(const float4*)(a1 + kk + 4);
            short8 af = pack8(w0, w1);
            short8 b0f, b1f;
            float c0[8] = {p0.x,p0.y,p0.z,p0.w,p1.x,p1.y,p1.z,p1.w};
            float c1[8] = {r0.x,r0.y,r0.z,r0.w,r1.x,r1.y,r1.z,r1.w};
#pragma unroll
            for (int j = 0; j < 8; ++j) {
                b0f[j] = f2bf(c0[j] * rd0);
                b1f[j] = f2bf(c1[j] * rd1);
            }
            acc0 = MFMA(af, b0f, acc0);
            acc1 = MFMA(af, b1f, acc1);
        }
#pragma unroll
        for (int r = 0; r < 4; ++r) {
            eplds[wv][i][q * 4 + r]      = acc0[r];
            eplds[wv][i + 16][q * 4 + r] = acc1[r];
        }
        int b = l >> 1, hf = l & 1;
        size_t obase = (size_t)b * 1024 + n0 + hf * 8;
#pragma unroll
        for (int t = 0; t < 8; ++t)
            atomicAdd(comb + obase + t, eplds[wv][b][hf * 8 + t]);
        if (nt == 0) {          // attn_weights output
            float* aw = out + 1024000;
            int bi = kc * 512 + tid * 2;
#pragma unroll
            for (int j = 0; j < 2; ++j) {
                int idx = bi + j;
                aw[idx] = es[idx] / den[idx >> 7];
            }
        }
    }
    gbar(bar, 5, NB);

    // ---- P6: comb(+b_comb) -> swizzled bf16 combh (dest-order) ----------
    if (gt < 32768) {
        int d = gt;
        int j = d & 7, ii = (d >> 3) & 15, qq = (d >> 7) & 3, T = d >> 9;
        int b = (T & 1) * 16 + ii;
        int k = (T >> 1) * 32 + qq * 8 + j;
        combh[d] = f2bf(comb[b * 1024 + k] + b_comb[k]);
    }
    gbar(bar, 6, NB);

    // ---- P7: vocab GEMM, one 16-row tile per wave, depth-2 pipeline -----
    {
        if (tid < 32) bsum[tid] = 0.f;
        __syncthreads();
        const int gw = gid * 4 + wv;    // 0..2047, 2000 tiles
        if (gw < 2000) {
            const int n0 = gw * 16;
            const float* wrow = W_out + (size_t)(n0 + i) * 1024 + q * 8;
            const short8* bp = (const short8*)combh + l;
            float4 wa = *(const float4*)(wrow);
            float4 wb = *(const float4*)(wrow + 4);
            short8 f0 = bp[0], f1 = bp[64];
            floatx4 acc0 = {0.f,0.f,0.f,0.f}, acc1 = {0.f,0.f,0.f,0.f};
#pragma unroll
            for (int kk = 0; kk < 992; kk += 32) {
                float4 na = *(const float4*)(wrow + kk + 32);
                float4 nb = *(const float4*)(wrow + kk + 36);
                int t2 = ((kk >> 5) + 1) * 2;
                short8 g0 = bp[t2 * 64];
                short8 g1 = bp[t2 * 64 + 64];
                short8 af = pack8(wa, wb);
                acc0 = MFMA(af, f0, acc0);
                acc1 = MFMA(af, f1, acc1);
                wa = na; wb = nb; f0 = g0; f1 = g1;
            }
            {
                short8 af = pack8(wa, wb);
                acc0 = MFMA(af, f0, acc0);
                acc1 = MFMA(af, f1, acc1);
            }
#pragma unroll
            for (int r = 0; r < 4; ++r) {
                eplds[wv][i][q * 4 + r]      = acc0[r];
                eplds[wv][i + 16][q * 4 + r] = acc1[r];
            }
            int b = l >> 1, hf = l & 1;
            float vo[8];
#pragma unroll
            for (int t = 0; t < 8; ++t) vo[t] = eplds[wv][b][hf * 8 + t];
            const float4* bo = (const float4*)(b_out + n0 + hf * 8);
            float4 bb0 = bo[0], bb1 = bo[1];
            vo[0] += bb0.x; vo[1] += bb0.y; vo[2] += bb0.z; vo[3] += bb0.w;
            vo[4] += bb1.x; vo[5] += bb1.y; vo[6] += bb1.z; vo[7] += bb1.w;
            float esum = 0.f;
#pragma unroll
            for (int t = 0; t < 8; ++t) esum += __expf(vo[t]);
            atomicAdd(&bsum[b], esum);
            float4 o0 = {vo[0], vo[1], vo[2], vo[3]};
            float4 o1 = {vo[4], vo[5], vo[6], vo[7]};
            float4* op = (float4*)(out + (size_t)b * VD + n0 + hf * 8);
            op[0] = o0; op[1] = o1;
        }
        __syncthreads();
        if (tid < 32) atomicAdd(sexp + tid, bsum[tid]);
    }
    gbar(bar, 7, NB);

    // ---- P8: log-softmax finalize ---------------------------------------
    {
        float4* o4 = (float4*)out;
#pragma unroll
        for (int rep = 0; rep < 2; ++rep) {
            int idx4 = gt + rep * 131072;
            if (idx4 < 256000) {
                int b = idx4 / 8000;
                float ls = logf(sexp[b]);
                float4 t = o4[idx4];
                t.x -= ls; t.y -= ls; t.z -= ls; t.w -= ls;
                o4[idx4] = t;
            }
        }
    }
}

// ---------------------------------------------------------------------------
extern "C" void kernel_launch(void* const* d_in, const int* in_sizes, int n_in,
                              void* d_out, int out_size, void* d_ws, size_t ws_size,
                              hipStream_t stream) {
    const float* x      = (const float*)d_in[0];
    const float* enc    = (const float*)d_in[1];
    const float* hid    = (const float*)d_in[2];
    const float* W_ih   = (const float*)d_in[3];
    const float* W_hh   = (const float*)d_in[4];
    const float* b_ih   = (const float*)d_in[5];
    const float* b_hh   = (const float*)d_in[6];
    const float* W_attn = (const float*)d_in[7];
    const float* W_comb = (const float*)d_in[9];
    const float* b_comb = (const float*)d_in[10];
    const float* W_out  = (const float*)d_in[11];
    const float* b_out  = (const float*)d_in[12];
    float* out = (float*)d_out;
    float* wsf = (float*)d_ws;

    hipMemsetAsync(d_ws, 0, 64, stream);   // zero the barrier counters
    mega<<<512, 256, 0, stream>>>(x, enc, hid, W_ih, W_hh, b_ih, b_hh,
                                  W_attn, W_comb, b_comb, W_out, b_out,
                                  out, wsf);
}

// Round 6
// 629.784 us; speedup vs baseline: 1.0403x; 1.0403x over previous
//
#include <hip/hip_runtime.h>
#include <hip/hip_bf16.h>
#include <math.h>

#define VD 32000

typedef __attribute__((ext_vector_type(8))) short short8;
typedef __attribute__((ext_vector_type(4))) float floatx4;

__device__ __forceinline__ short f2bf(float f) {
    unsigned u = __builtin_bit_cast(unsigned, f);
    u += 0x7FFFu + ((u >> 16) & 1u);
    return (short)(u >> 16);
}
__device__ __forceinline__ float bf2f(short h) {
    unsigned u = ((unsigned)(unsigned short)h) << 16;
    return __builtin_bit_cast(float, u);
}
__device__ __forceinline__ unsigned pack2(float a, float b) {
    unsigned ua = __builtin_bit_cast(unsigned, a) + 0x8000u;
    unsigned ub = __builtin_bit_cast(unsigned, b) + 0x8000u;
    return (ub & 0xffff0000u) | (ua >> 16);
}
__device__ __forceinline__ void split8(const float4 u0, const float4 u1,
                                       short8* hi, short8* lo) {
    float f[8] = {u0.x, u0.y, u0.z, u0.w, u1.x, u1.y, u1.z, u1.w};
#pragma unroll
    for (int j = 0; j < 8; ++j) {
        short h = f2bf(f[j]);
        (*hi)[j] = h;
        (*lo)[j] = f2bf(f[j] - bf2f(h));
    }
}
__device__ __forceinline__ short8 pack8(const float4 u0, const float4 u1) {
    union { unsigned u[4]; short8 s; } pk;
    pk.u[0] = pack2(u0.x, u0.y); pk.u[1] = pack2(u0.z, u0.w);
    pk.u[2] = pack2(u1.x, u1.y); pk.u[3] = pack2(u1.z, u1.w);
    return pk.s;
}

#define MFMA(a, b, c) __builtin_amdgcn_mfma_f32_16x16x32_bf16(a, b, c, 0, 0, 0)

// Grid barrier (proven in R5): 512 blocks @ launch_bounds(256,2) + 17.3 KB LDS
// are 2-per-CU co-resident on 256 CUs. Backoff sleep cuts cacheline pounding.
__device__ __forceinline__ void gbar(unsigned* bar, int ph, unsigned nb) {
    __syncthreads();
    if (threadIdx.x == 0) {
        __threadfence();
        __atomic_fetch_add(bar + ph, 1u, __ATOMIC_RELAXED);
        while (__atomic_load_n(bar + ph, __ATOMIC_RELAXED) < nb)
            __builtin_amdgcn_s_sleep(8);
        __threadfence();
    }
    __syncthreads();
}

// Frag-pattern: for 16x16x32 bf16 MFMA, lane l (i=l&15, q=l>>4) holds
// A[m=i][k=q*8+j] and B[k=q*8+j][n=i] -- 8 consecutive k of one row.
// combh layout: element M[b][k] at ((t*2+mt)*64 + q*16 + i)*8 + j with
// t=k/32, q=(k%32)/8, j=k%8, mt=b/16, i=b%16.

__global__ __launch_bounds__(256, 2) void mega(
    const float* __restrict__ x0, const float* __restrict__ enc,
    const float* __restrict__ h0,
    const float* __restrict__ W_ih, const float* __restrict__ W_hh,
    const float* __restrict__ b_ih, const float* __restrict__ b_hh,
    const float* __restrict__ W_attn, const float* __restrict__ W_comb,
    const float* __restrict__ b_comb, const float* __restrict__ W_out,
    const float* __restrict__ b_out, float* __restrict__ out,
    float* __restrict__ ws)
{
    const int gid = blockIdx.x, tid = threadIdx.x;
    const unsigned NB = gridDim.x;          // 512
    const int gt = gid * 256 + tid;
    const int wv = tid >> 6, l = tid & 63;
    const int i = l & 15, q = l >> 4;

    unsigned* bar = (unsigned*)ws;        // 16 counters (memset-zeroed)
    float* wsf   = ws + 16;
    float* xg    = wsf;                   // 98304  (memset-zeroed region start)
    float* hg    = xg + 98304;            // 98304
    float* v     = hg + 98304;            // 32768
    float* num   = v + 32768;             // 32768
    float* den   = num + 32768;           // 32
    float* sexp  = den + 32;              // 32
    float* comb  = sexp + 32;             // 32768  -- zero region: 294976 floats
    float* es    = comb + 32768;          // 4096
    float* dec   = es + 4096;             // 32768
    short* combh = (short*)(dec + 32768); // 32768 shorts

    __shared__ float stage[32][65];
    __shared__ float eplds[4][32][17];
    __shared__ float bsum[32];
    __shared__ float red[4][8];
    __shared__ float esl[8];

    // ---- P1: gate GEMMs  xg += x0.W_ih^T, hg += h0.W_hh^T (hi/lo) -------
    if (gid < 384) {
        const int z = gid & 1, kc = (gid >> 1) & 3, nt = gid >> 3;
        const int n0 = nt * 64 + wv * 16, k0 = kc * 256;
        const float* W   = z ? W_hh : W_ih;
        const float* act = z ? h0   : x0;
        float*       o   = z ? hg   : xg;
        const float* wrow = W + (size_t)(n0 + i) * 1024 + q * 8;
        const float* a0 = act + (size_t)i * 1024 + q * 8;
        const float* a1 = act + (size_t)(16 + i) * 1024 + q * 8;
        floatx4 acc0 = {0.f,0.f,0.f,0.f}, acc1 = {0.f,0.f,0.f,0.f};
#pragma unroll 4
        for (int kk = k0; kk < k0 + 256; kk += 32) {
            float4 w0 = *(const float4*)(wrow + kk);
            float4 w1 = *(const float4*)(wrow + kk + 4);
            float4 p0 = *(const float4*)(a0 + kk);
            float4 p1 = *(const float4*)(a0 + kk + 4);
            float4 r0 = *(const float4*)(a1 + kk);
            float4 r1 = *(const float4*)(a1 + kk + 4);
            short8 ah, al, b0h, b0l, b1h, b1l;
            split8(w0, w1, &ah, &al);
            split8(p0, p1, &b0h, &b0l);
            split8(r0, r1, &b1h, &b1l);
            acc0 = MFMA(ah, b0h, acc0);
            acc0 = MFMA(ah, b0l, acc0);
            acc0 = MFMA(al, b0h, acc0);
            acc1 = MFMA(ah, b1h, acc1);
            acc1 = MFMA(ah, b1l, acc1);
            acc1 = MFMA(al, b1h, acc1);
        }
#pragma unroll
        for (int r = 0; r < 4; ++r) {
            eplds[wv][i][q * 4 + r]      = acc0[r];   // D[m=q*4+r][n=i]
            eplds[wv][i + 16][q * 4 + r] = acc1[r];
        }
        int b = l >> 1, hf = l & 1;
        size_t obase = (size_t)b * 3072 + n0 + hf * 8;
#pragma unroll
        for (int t = 0; t < 8; ++t)
            atomicAdd(o + obase + t, eplds[wv][b][hf * 8 + t]);
    }
    gbar(bar, 0, NB);

    // ---- P2: GRU gate fusion -> dec (fp32) ------------------------------
    if (gt < 32768) {
        int b = gt >> 10, h = gt & 1023;
        const float* xp = xg + (size_t)b * 3072 + h;
        const float* hp = hg + (size_t)b * 3072 + h;
        float r = 1.f / (1.f + __expf(-(xp[0] + b_ih[h] + hp[0] + b_hh[h])));
        float z = 1.f / (1.f + __expf(-(xp[1024] + b_ih[1024 + h] +
                                        hp[1024] + b_hh[1024 + h])));
        float n = tanhf(xp[2048] + b_ih[2048 + h] +
                        r * (hp[2048] + b_hh[2048 + h]));
        dec[gt] = (1.f - z) * n + z * h0[gt];
    }
    gbar(bar, 1, NB);

    // ---- P3: v[b][e] += dec[b][:].W_attn[:][1024+e] ---------------------
    if (gid < 256) {
        const int et = gid & 15, kc = gid >> 4;
        const int e0 = et * 64, k0 = kc * 64;
        const int sr = tid >> 3, sc = (tid & 7) * 8;
        floatx4 acc0 = {0.f,0.f,0.f,0.f}, acc1 = {0.f,0.f,0.f,0.f};
#pragma unroll
        for (int t = 0; t < 2; ++t) {
            int kb = k0 + t * 32;
            const float* src = W_attn + (size_t)(kb + sr) * 2048 + 1024 + e0 + sc;
            float4 s0 = *(const float4*)src;
            float4 s1 = *(const float4*)(src + 4);
            __syncthreads();
            *(float4*)&stage[sr][sc]     = s0;
            *(float4*)&stage[sr][sc + 4] = s1;
            __syncthreads();
            short8 Ah0, Al0, Ah1, Al1, Bh, Bl;
            {
                const float* dp = dec + (size_t)i * 1024 + kb + q * 8;
                split8(*(const float4*)dp, *(const float4*)(dp + 4), &Ah0, &Al0);
                const float* dp1 = dec + (size_t)(16 + i) * 1024 + kb + q * 8;
                split8(*(const float4*)dp1, *(const float4*)(dp1 + 4), &Ah1, &Al1);
            }
#pragma unroll
            for (int j = 0; j < 8; ++j) {
                float f = stage[q * 8 + j][wv * 16 + i];
                unsigned u = __builtin_bit_cast(unsigned, f);
                float hif = __builtin_bit_cast(float, u & 0xffff0000u);
                Bh[j] = (short)(u >> 16);
                Bl[j] = (short)(__builtin_bit_cast(unsigned, f - hif) >> 16);
            }
            acc0 = MFMA(Ah0, Bh, acc0);
            acc0 = MFMA(Ah0, Bl, acc0);
            acc0 = MFMA(Al0, Bh, acc0);
            acc1 = MFMA(Ah1, Bh, acc1);
            acc1 = MFMA(Ah1, Bl, acc1);
            acc1 = MFMA(Al1, Bh, acc1);
        }
#pragma unroll
        for (int r = 0; r < 4; ++r) {
            atomicAdd(v + (size_t)(q * 4 + r) * 1024 + e0 + wv * 16 + i, acc0[r]);
            atomicAdd(v + (size_t)(16 + q * 4 + r) * 1024 + e0 + wv * 16 + i, acc1[r]);
        }
    }
    gbar(bar, 2, NB);

    // ---- P4: scores + shift-free softmax partials + context partials ----
    {
        int b = gid & 31, s0 = (gid >> 5) * 8;
        float4 vv = *((const float4*)(v + (size_t)b * 1024) + tid);
        float4 e8[8];
        float part[8];
#pragma unroll
        for (int s = 0; s < 8; ++s) {
            float4 e4 = *((const float4*)(enc + ((size_t)(s0 + s) * 32 + b) * 1024) + tid);
            e8[s] = e4;
            part[s] = e4.x * vv.x + e4.y * vv.y + e4.z * vv.z + e4.w * vv.w;
        }
#pragma unroll
        for (int s = 0; s < 8; ++s) {
            float p = part[s];
            for (int o = 32; o; o >>= 1) p += __shfl_down(p, o);
            if (l == 0) red[wv][s] = p;
        }
        __syncthreads();
        if (tid < 8) {
            float sc_ = red[0][tid] + red[1][tid] + red[2][tid] + red[3][tid];
            float e = __expf(sc_);
            esl[tid] = e;
            es[b * 128 + s0 + tid] = e;
        }
        __syncthreads();
        if (tid == 0) {
            float ds = 0.f;
#pragma unroll
            for (int s = 0; s < 8; ++s) ds += esl[s];
            atomicAdd(den + b, ds);
        }
        float n0 = 0.f, n1 = 0.f, n2 = 0.f, n3 = 0.f;
#pragma unroll
        for (int s = 0; s < 8; ++s) {
            float e = esl[s];
            n0 += e * e8[s].x; n1 += e * e8[s].y;
            n2 += e * e8[s].z; n3 += e * e8[s].w;
        }
        float* np = num + (size_t)b * 1024 + tid * 4;
        atomicAdd(np, n0); atomicAdd(np + 1, n1);
        atomicAdd(np + 2, n2); atomicAdd(np + 3, n3);
    }
    gbar(bar, 3, NB);

    // ---- P5: comb GEMM (cat built per-lane) + aw_out --------------------
    if (gid < 128) {
        const int nt = gid & 15, kc = gid >> 4;
        const int n0 = nt * 64 + wv * 16, k0 = kc * 256;
        const bool isnum = kc >= 4;
        const float* base = isnum ? num : x0;
        const int kb = isnum ? k0 - 1024 : k0;
        float rd0 = 1.f, rd1 = 1.f;
        if (isnum) { rd0 = 1.f / den[i]; rd1 = 1.f / den[16 + i]; }
        const float* wrow = W_comb + (size_t)(n0 + i) * 2048 + k0 + q * 8;
        const float* a0 = base + (size_t)i * 1024 + kb + q * 8;
        const float* a1 = base + (size_t)(16 + i) * 1024 + kb + q * 8;
        floatx4 acc0 = {0.f,0.f,0.f,0.f}, acc1 = {0.f,0.f,0.f,0.f};
#pragma unroll 4
        for (int kk = 0; kk < 256; kk += 32) {
            float4 w0 = *(const float4*)(wrow + kk);
            float4 w1 = *(const float4*)(wrow + kk + 4);
            float4 p0 = *(const float4*)(a0 + kk);
            float4 p1 = *(const float4*)(a0 + kk + 4);
            float4 r0 = *(const float4*)(a1 + kk);
            float4 r1 = *(const float4*)(a1 + kk + 4);
            short8 af = pack8(w0, w1);
            short8 b0f, b1f;
            float c0[8] = {p0.x,p0.y,p0.z,p0.w,p1.x,p1.y,p1.z,p1.w};
            float c1[8] = {r0.x,r0.y,r0.z,r0.w,r1.x,r1.y,r1.z,r1.w};
#pragma unroll
            for (int j = 0; j < 8; ++j) {
                b0f[j] = f2bf(c0[j] * rd0);
                b1f[j] = f2bf(c1[j] * rd1);
            }
            acc0 = MFMA(af, b0f, acc0);
            acc1 = MFMA(af, b1f, acc1);
        }
#pragma unroll
        for (int r = 0; r < 4; ++r) {
            eplds[wv][i][q * 4 + r]      = acc0[r];
            eplds[wv][i + 16][q * 4 + r] = acc1[r];
        }
        int b = l >> 1, hf = l & 1;
        size_t obase = (size_t)b * 1024 + n0 + hf * 8;
#pragma unroll
        for (int t = 0; t < 8; ++t)
            atomicAdd(comb + obase + t, eplds[wv][b][hf * 8 + t]);
        if (nt == 0) {          // attn_weights output
            float* aw = out + 1024000;
            int bi = kc * 512 + tid * 2;
#pragma unroll
            for (int j = 0; j < 2; ++j) {
                int idx = bi + j;
                aw[idx] = es[idx] / den[idx >> 7];
            }
        }
    }
    gbar(bar, 4, NB);

    // ---- P6: comb(+b_comb) -> swizzled bf16 combh (dest-order) ----------
    if (gt < 32768) {
        int d = gt;
        int j = d & 7, ii = (d >> 3) & 15, qq = (d >> 7) & 3, T = d >> 9;
        int b = (T & 1) * 16 + ii;
        int k = (T >> 1) * 32 + qq * 8 + j;
        combh[d] = f2bf(comb[b * 1024 + k] + b_comb[k]);
    }
    gbar(bar, 5, NB);

    // ---- P7: vocab GEMM, 16-row tile per wave, DEPTH-6 ring pipeline ----
    {
        if (tid < 32) bsum[tid] = 0.f;
        __syncthreads();
        const int gw = gid * 4 + wv;    // 0..2047, 2000 tiles
        if (gw < 2000) {
            const int n0 = gw * 16;
            const float* wrow = W_out + (size_t)(n0 + i) * 1024 + q * 8;
            const short8* bp = (const short8*)combh + l;
            constexpr int D = 6;
            float4 wa[D], wb[D];
            short8 c0[D], c1[D];
#pragma unroll
            for (int d = 0; d < D; ++d) {
                wa[d] = *(const float4*)(wrow + d * 32);
                wb[d] = *(const float4*)(wrow + d * 32 + 4);
                c0[d] = bp[d * 128];
                c1[d] = bp[d * 128 + 64];
            }
            floatx4 acc0 = {0.f,0.f,0.f,0.f}, acc1 = {0.f,0.f,0.f,0.f};
#pragma unroll
            for (int kk = 0; kk < 32; ++kk) {
                const int s = kk % D;
                short8 af = pack8(wa[s], wb[s]);
                acc0 = MFMA(af, c0[s], acc0);
                acc1 = MFMA(af, c1[s], acc1);
                const int nk = kk + D;
                if (nk < 32) {
                    wa[s] = *(const float4*)(wrow + nk * 32);
                    wb[s] = *(const float4*)(wrow + nk * 32 + 4);
                    c0[s] = bp[nk * 128];
                    c1[s] = bp[nk * 128 + 64];
                }
            }
#pragma unroll
            for (int r = 0; r < 4; ++r) {
                eplds[wv][i][q * 4 + r]      = acc0[r];
                eplds[wv][i + 16][q * 4 + r] = acc1[r];
            }
            int b = l >> 1, hf = l & 1;
            float vo[8];
#pragma unroll
            for (int t = 0; t < 8; ++t) vo[t] = eplds[wv][b][hf * 8 + t];
            const float4* bo = (const float4*)(b_out + n0 + hf * 8);
            float4 bb0 = bo[0], bb1 = bo[1];
            vo[0] += bb0.x; vo[1] += bb0.y; vo[2] += bb0.z; vo[3] += bb0.w;
            vo[4] += bb1.x; vo[5] += bb1.y; vo[6] += bb1.z; vo[7] += bb1.w;
            float esum = 0.f;
#pragma unroll
            for (int t = 0; t < 8; ++t) esum += __expf(vo[t]);
            atomicAdd(&bsum[b], esum);
            float4 o0 = {vo[0], vo[1], vo[2], vo[3]};
            float4 o1 = {vo[4], vo[5], vo[6], vo[7]};
            float4* op = (float4*)(out + (size_t)b * VD + n0 + hf * 8);
            op[0] = o0; op[1] = o1;
        }
        __syncthreads();
        if (tid < 32) atomicAdd(sexp + tid, bsum[tid]);
    }
    gbar(bar, 6, NB);

    // ---- P8: log-softmax finalize ---------------------------------------
    {
        float4* o4 = (float4*)out;
#pragma unroll
        for (int rep = 0; rep < 2; ++rep) {
            int idx4 = gt + rep * 131072;
            if (idx4 < 256000) {
                int b = idx4 / 8000;
                float ls = logf(sexp[b]);
                float4 t = o4[idx4];
                t.x -= ls; t.y -= ls; t.z -= ls; t.w -= ls;
                o4[idx4] = t;
            }
        }
    }
}

// ---------------------------------------------------------------------------
extern "C" void kernel_launch(void* const* d_in, const int* in_sizes, int n_in,
                              void* d_out, int out_size, void* d_ws, size_t ws_size,
                              hipStream_t stream) {
    const float* x      = (const float*)d_in[0];
    const float* enc    = (const float*)d_in[1];
    const float* hid    = (const float*)d_in[2];
    const float* W_ih   = (const float*)d_in[3];
    const float* W_hh   = (const float*)d_in[4];
    const float* b_ih   = (const float*)d_in[5];
    const float* b_hh   = (const float*)d_in[6];
    const float* W_attn = (const float*)d_in[7];
    const float* W_comb = (const float*)d_in[9];
    const float* b_comb = (const float*)d_in[10];
    const float* W_out  = (const float*)d_in[11];
    const float* b_out  = (const float*)d_in[12];
    float* out = (float*)d_out;
    float* wsf = (float*)d_ws;

    // zero barrier counters (64 B) + accumulator region (294976 floats)
    hipMemsetAsync(d_ws, 0, 64 + 294976u * 4, stream);
    mega<<<512, 256, 0, stream>>>(x, enc, hid, W_ih, W_hh, b_ih, b_hh,
                                  W_attn, W_comb, b_comb, W_out, b_out,
                                  out, wsf);
}